// Round 8
// baseline (134.199 us; speedup 1.0000x reference)
//
#include <hip/hip_runtime.h>

// Chamfer loss via MFMA, N=4, P1=P2=8192, D=3, K=1.
// d2 = |x|^2 - 2x.y + |y|^2 packed into one mfma_f32_16x16x32_bf16 K-dim:
//  A(row m) k0-7 : [-2xh0,-2xh1,-2xh2, -2xh0,-2xh1,-2xh2, -2xl0,-2xl1]
//           k8-15: [-2xl2, 1, 1, -2xl0,-2xl1,-2xl2, x2h, x2l]
//  B(col n) k0-7 : [ yh0,  yh1,  yh2,  yl0,  yl1,  yl2,  yh0, yh1]
//           k8-15: [ yh2, w2h, w2l,  yl0,  yl1,  yl2,  1,   1 ]   (w2=|y|^2, 1e30 if padded)
//  k16-31 zero. Sum_k A*B = -2(xh+xl).(yh+yl) + |y|^2 + |x|^2 = d2 (residual ~2^-18).
// Verified layouts (guide m89/m91/m120): A[m=lane&15][k=(lane>>4)*8+j]; C/D col=lane&15,
// row=(lane>>4)*4+reg. One MFMA = 256 complete d2 candidates; min via v_pk_min_f32.
typedef __attribute__((ext_vector_type(8))) short short8;
typedef __attribute__((ext_vector_type(4))) float f32x4;
typedef __attribute__((ext_vector_type(2))) float f32x2;

constexpr int N = 4;
constexpr int P = 8192;
constexpr int NSEG = 8;
constexpr int SEGC = P / NSEG;     // 1024 cols per segment
constexpr int RB = 512;            // rows per block
constexpr int NRB = P / RB;        // 16
constexpr int G = 8;               // 16-row groups per wave (128 rows/wave, 4 waves)
constexpr int TILEC = 256;         // cols per LDS tile = 16 groups = 512 recs = 8 KB
constexpr unsigned short ONEB = 0x3F80;          // 1.0 in bf16
constexpr size_t RECS_PER_SLAB = (size_t)P * 2;  // 16B records per (side,b)

__device__ inline unsigned short f2bf(float f) {       // RNE float->bf16
    unsigned u = __float_as_uint(f);
    return (unsigned short)((u + 0x7fffu + ((u >> 16) & 1u)) >> 16);
}
__device__ inline float bf2f(unsigned short h) { return __uint_as_float((unsigned)h << 16); }
__device__ inline uint4 pack8(unsigned short a, unsigned short b, unsigned short c,
                              unsigned short d, unsigned short e, unsigned short f,
                              unsigned short g, unsigned short h) {
    return make_uint4((unsigned)a | ((unsigned)b << 16), (unsigned)c | ((unsigned)d << 16),
                      (unsigned)e | ((unsigned)f << 16), (unsigned)g | ((unsigned)h << 16));
}

__global__ __launch_bounds__(256) void chamfer_prep_kernel(
    const float* __restrict__ pred, const float* __restrict__ targ,
    const int* __restrict__ lens, uint4* __restrict__ apack, uint4* __restrict__ bpack)
{
    const int i = blockIdx.x * 256 + threadIdx.x;    // 2*N*P
    const int side = i >> 15, b = (i >> 13) & 3, j = i & (P - 1);
    const float* s = (side ? targ : pred) + ((size_t)b * P + j) * 3;
    const float x = s[0], y = s[1], z = s[2];
    const float x2 = fmaf(x, x, fmaf(y, y, z * z));
    const float w2 = (side == 1 && j >= lens[b]) ? 1e30f : x2;  // col-role |y|^2, padded->1e30

    const unsigned short xh = f2bf(x), yh = f2bf(y), zh = f2bf(z);
    const float xhf = bf2f(xh), yhf = bf2f(yh), zhf = bf2f(zh);
    const unsigned short xl = f2bf(x - xhf), yl = f2bf(y - yhf), zl = f2bf(z - zhf);
    const unsigned short x2h = f2bf(x2), x2l = f2bf(x2 - bf2f(x2h));
    const unsigned short w2h = f2bf(w2), w2l = f2bf(w2 - bf2f(w2h));
    // -2*h is exact in bf16 (sign+exponent change only)
    const unsigned short nxh = f2bf(-2.f * xhf), nyh = f2bf(-2.f * yhf), nzh = f2bf(-2.f * zhf);
    const unsigned short nxl = f2bf(-2.f * bf2f(xl)), nyl = f2bf(-2.f * bf2f(yl)),
                         nzl = f2bf(-2.f * bf2f(zl));

    const size_t slab = (size_t)(side * N + b) * RECS_PER_SLAB;
    const int gidx = j >> 4, lane = j & 15;
    apack[slab + gidx * 32 + lane]      = pack8(nxh, nyh, nzh, nxh, nyh, nzh, nxl, nyl);
    apack[slab + gidx * 32 + 16 + lane] = pack8(nzl, ONEB, ONEB, nxl, nyl, nzl, x2h, x2l);
    bpack[slab + gidx * 32 + lane]      = pack8(yh, yl? 0:0, 0,0,0,0,0,0); // placeholder, fixed below
    // (real B records)
    bpack[slab + gidx * 32 + lane]      = pack8(xh, yh, zh, xl, yl, zl, xh, yh);
    bpack[slab + gidx * 32 + 16 + lane] = pack8(zh, w2h, w2l, xl, yl, zl, ONEB, ONEB);
}

__global__ __launch_bounds__(256) void chamfer_min_kernel(
    const int* __restrict__ lens, const uint4* __restrict__ apack,
    const uint4* __restrict__ bpack, float* __restrict__ partial)
{
    int id = blockIdx.x;                       // 2*N*NRB*NSEG = 1024
    const int seg = id & 7;  id >>= 3;
    const int rb  = id & 15; id >>= 4;
    const int b   = id & 3;  id >>= 2;
    const int dir = id;                        // 0: pred rows / targ cols
    const int L   = lens[b];
    const int tid = threadIdx.x;
    const int wv = tid >> 6, lane = tid & 63;

    float* slot = partial + (((size_t)dir * N + b) * NSEG + seg) * P + rb * RB;
    if (dir == 1 && rb * RB >= L) return;              // padded rows: never read
    if (dir == 0 && seg * SEGC >= L) {                 // no valid cols: sentinel
        slot[tid * 2] = 1e30f; slot[tid * 2 + 1] = 1e30f; return;
    }

    const uint4* aslab = apack + (size_t)((dir == 0 ? 0 : 1) * N + b) * RECS_PER_SLAB;
    const uint4* bslab = bpack + (size_t)((dir == 0 ? 1 : 0) * N + b) * RECS_PER_SLAB;

    short8 afr[G];
    #pragma unroll
    for (int g = 0; g < G; ++g) {
        short8 v = short8{0, 0, 0, 0, 0, 0, 0, 0};     // k16-31 lanes stay zero
        if (lane < 32) v = ((const short8*)aslab)[(rb * 32 + wv * 8 + g) * 16 * 2 / 32 * 32 + lane]; // see below
        afr[g] = v;
    }
    // NOTE: record index = gidx*32 + lane (lane<32 spans both quads), gidx = rb*32+wv*8+g
    #pragma unroll
    for (int g = 0; g < G; ++g) {
        short8 v = short8{0, 0, 0, 0, 0, 0, 0, 0};
        if (lane < 32) v = ((const short8*)aslab)[(rb * 32 + wv * 8 + g) * 32 + lane];
        afr[g] = v;
    }

    f32x2 best[G][2];
    #pragma unroll
    for (int g = 0; g < G; ++g) { best[g][0] = (f32x2){1e30f, 1e30f}; best[g][1] = (f32x2){1e30f, 1e30f}; }

    __shared__ uint4 sbuf[TILEC * 2 + 1];              // 512 recs + zero slot
    if (tid == 0) sbuf[TILEC * 2] = make_uint4(0, 0, 0, 0);

    const int ldsi0  = (lane < 32) ? lane : TILEC * 2; // lanes>=32 read zeros (k16-31)
    const int ldstep = (lane < 32) ? 32 : 0;

    for (int t = 0; t < SEGC / TILEC; ++t) {           // 4 tiles
        const uint4* src = bslab + (size_t)(seg * 64 + t * 16) * 32;
        __syncthreads();                               // prev readers done / zero slot visible
        sbuf[tid] = src[tid];
        sbuf[tid + 256] = src[tid + 256];
        __syncthreads();

        #pragma unroll 2
        for (int gl = 0; gl < 16; ++gl) {
            const short8 bfr = ((const short8*)sbuf)[ldsi0 + gl * ldstep];
            #pragma unroll
            for (int g = 0; g < G; ++g) {
                const f32x4 d = __builtin_amdgcn_mfma_f32_16x16x32_bf16(
                    afr[g], bfr, (f32x4){0.f, 0.f, 0.f, 0.f}, 0, 0, 0);
                best[g][0] = __builtin_elementwise_min(best[g][0], (f32x2){d[0], d[1]});
                best[g][1] = __builtin_elementwise_min(best[g][1], (f32x2){d[2], d[3]});
            }
        }
    }

    // cross-lane: 16 lanes (cols) share each row -> butterfly min within 16-lane groups
    #pragma unroll
    for (int g = 0; g < G; ++g) {
        float v0 = best[g][0][0], v1 = best[g][0][1], v2 = best[g][1][0], v3 = best[g][1][1];
        #pragma unroll
        for (int m = 1; m < 16; m <<= 1) {
            v0 = fminf(v0, __shfl_xor(v0, m, 16));
            v1 = fminf(v1, __shfl_xor(v1, m, 16));
            v2 = fminf(v2, __shfl_xor(v2, m, 16));
            v3 = fminf(v3, __shfl_xor(v3, m, 16));
        }
        if ((lane & 15) == 0) {                        // row = (lane>>4)*4 + reg
            float* r = slot + wv * 128 + g * 16 + (lane >> 4) * 4;
            r[0] = v0; r[1] = v1; r[2] = v2; r[3] = v3;
        }
    }
}

__global__ __launch_bounds__(256) void chamfer_reduce_kernel(
    const float* __restrict__ partial, const int* __restrict__ lens,
    float* __restrict__ out)
{
    const int item = blockIdx.x * 256 + threadIdx.x;   // 2*N*P
    const int dir = item >> 15;
    const int b   = (item >> 13) & (N - 1);
    const int p   = item & (P - 1);
    const int L   = lens[b];

    float c = 0.f;
    if (dir == 0 || p < L) {
        const float* base = partial + (((size_t)dir * N + b) * NSEG) * P + p;
        float v = base[0];
        #pragma unroll
        for (int s = 1; s < NSEG; ++s) v = fminf(v, base[(size_t)s * P]);
        v = fmaxf(v, 0.f);
        c = dir ? v / ((float)L * (float)N) : v * (1.0f / ((float)P * (float)N));
    }
    #pragma unroll
    for (int off = 32; off; off >>= 1) c += __shfl_down(c, off, 64);
    __shared__ float acc[4];
    if ((threadIdx.x & 63) == 0) acc[threadIdx.x >> 6] = c;
    __syncthreads();
    if (threadIdx.x == 0) atomicAdd(out, acc[0] + acc[1] + acc[2] + acc[3]);
}

extern "C" void kernel_launch(void* const* d_in, const int* in_sizes, int n_in,
                              void* d_out, int out_size, void* d_ws, size_t ws_size,
                              hipStream_t stream)
{
    const float* pred = (const float*)d_in[0];
    const float* targ = (const float*)d_in[1];
    const int*   lens = (const int*)d_in[2];
    float* out = (float*)d_out;

    uint4* apack = (uint4*)d_ws;                                  // 2 MB
    uint4* bpack = apack + (size_t)2 * N * RECS_PER_SLAB;         // 2 MB
    float* partial = (float*)(bpack + (size_t)2 * N * RECS_PER_SLAB); // 2 MB

    hipMemsetAsync(out, 0, out_size * sizeof(float), stream);
    chamfer_prep_kernel<<<(2 * N * P) / 256, 256, 0, stream>>>(pred, targ, lens, apack, bpack);
    chamfer_min_kernel<<<2 * N * NRB * NSEG, 256, 0, stream>>>(lens, apack, bpack, partial);
    chamfer_reduce_kernel<<<(2 * N * P) / 256, 256, 0, stream>>>(partial, lens, out);
}

// Round 9
// 123.554 us; speedup vs baseline: 1.0862x; 1.0862x over previous
//
#include <hip/hip_runtime.h>

// Chamfer loss via mfma_f32_32x32x16_bf16 (K=16 fully used, 1024 cand/MFMA).
// d2 = -2x.y + |x|^2 + |y|^2, error-compensated bf16 split (x=xh+xl):
// k0-2: -2xh_c*yh_c  k3-5: -2xh_c*yl_c  k6-8: -2xl_c*yh_c  k9-11: -2xl_c*yl_c
// k12: x2h*1  k13: x2l*1  k14: 1*w2h  k15: 1*w2l   (w2=|col|^2, 1e30 if padded)
// Layouts: A[m=lane&31][k=8*(lane>>5)+j], B[n=lane&31][k=8*(lane>>5)+j];
// C/D col=lane&31, row=(reg&3)+8*(reg>>2)+4*(lane>>5)  [verified m74/m101].
typedef __attribute__((ext_vector_type(8))) short short8;
typedef __attribute__((ext_vector_type(16))) float f32x16;

constexpr int N = 4;
constexpr int P = 8192;
constexpr int NSEG = 4;
constexpr int SEGC = P / NSEG;       // 2048 cols per segment
constexpr int GA = 2;                // A-frags (32 rows each) per wave
constexpr int ROWS = 4 * GA * 32;    // 256 rows per block
constexpr int RB = P / ROWS;         // 32 row-blocks
constexpr size_t RECS = (size_t)2 * P;   // uint4 records per (side,b) slab
constexpr unsigned short ONEB = 0x3F80;  // 1.0 bf16

__device__ inline unsigned short f2bf(float f) {      // RNE float->bf16
    unsigned u = __float_as_uint(f);
    return (unsigned short)((u + 0x7fffu + ((u >> 16) & 1u)) >> 16);
}
__device__ inline float bf2f(unsigned short h) { return __uint_as_float((unsigned)h << 16); }
__device__ inline uint4 pack8(unsigned short a, unsigned short b, unsigned short c,
                              unsigned short d, unsigned short e, unsigned short f,
                              unsigned short g, unsigned short h) {
    return make_uint4((unsigned)a | ((unsigned)b << 16), (unsigned)c | ((unsigned)d << 16),
                      (unsigned)e | ((unsigned)f << 16), (unsigned)g | ((unsigned)h << 16));
}

// B packs: per 32-col group, rec[r<32]=k0-7 of col r, rec[r+32]=k8-15 of col r.
__global__ __launch_bounds__(256) void chamfer_prep_kernel(
    const float* __restrict__ pred, const float* __restrict__ targ,
    const int* __restrict__ lens, uint4* __restrict__ bpack)
{
    const int i = blockIdx.x * 256 + threadIdx.x;     // 2*N*P
    const int side = i >> 15, b = (i >> 13) & 3, j = i & (P - 1);
    const float* s = (side ? targ : pred) + ((size_t)b * P + j) * 3;
    const float x = s[0], y = s[1], z = s[2];
    const float x2 = fmaf(x, x, fmaf(y, y, z * z));
    const float w2 = (side == 1 && j >= lens[b]) ? 1e30f : x2;
    const unsigned short h0 = f2bf(x), h1 = f2bf(y), h2 = f2bf(z);
    const unsigned short l0 = f2bf(x - bf2f(h0)), l1 = f2bf(y - bf2f(h1)),
                         l2 = f2bf(z - bf2f(h2));
    const unsigned short w2h = f2bf(w2), w2l = f2bf(w2 - bf2f(w2h));
    uint4* dst = bpack + (size_t)(side * N + b) * RECS + (size_t)(j >> 5) * 64 + (j & 31);
    dst[0]  = pack8(h0, h1, h2, l0, l1, l2, h0, h1);
    dst[32] = pack8(h2, l0, l1, l2, ONEB, ONEB, w2h, w2l);
}

__global__ __launch_bounds__(256) void chamfer_min_kernel(
    const float* __restrict__ pred, const float* __restrict__ targ,
    const int* __restrict__ lens, const uint4* __restrict__ bpack,
    float* __restrict__ partial)
{
    int id = blockIdx.x;                 // 2*4*32*4 = 1024
    const int seg = id & (NSEG - 1); id >>= 2;
    const int rb  = id & (RB - 1);   id >>= 5;
    const int b   = id & 3;          id >>= 2;
    const int dir = id;                  // 0: pred rows / targ cols
    const int row0 = rb * ROWS;
    const int c0   = seg * SEGC;
    const int L    = lens[b];
    const int tid  = threadIdx.x;
    const int wv = tid >> 6, lane = tid & 63;
    const int m = lane & 31, kh = lane >> 5;

    float* slot = partial + (((size_t)dir * N + b) * NSEG + seg) * P + row0;
    if (dir == 1 && row0 >= L) return;               // padded rows: never read
    if (dir == 0 && c0 >= L) { slot[tid] = 1e30f; return; }

    const float* rsrc = (dir == 0 ? pred : targ) + (size_t)b * P * 3;
    const uint4* bslab = bpack + (size_t)((dir == 0 ? 1 : 0) * N + b) * RECS;

    // Build A-frags in-register from raw row coords (prologue only).
    short8 afr[GA];
    f32x16 best[GA];
    #pragma unroll
    for (int g = 0; g < GA; ++g) {
        const float* p = rsrc + (size_t)(row0 + (wv * GA + g) * 32 + m) * 3;
        const float x = p[0], y = p[1], z = p[2];
        const float x2 = fmaf(x, x, fmaf(y, y, z * z));
        const unsigned short xh = f2bf(x), yh = f2bf(y), zh = f2bf(z);
        const unsigned short nxh = f2bf(-2.f * bf2f(xh)), nyh = f2bf(-2.f * bf2f(yh)),
                             nzh = f2bf(-2.f * bf2f(zh));
        const unsigned short nxl = f2bf(-2.f * (x - bf2f(xh))),
                             nyl = f2bf(-2.f * (y - bf2f(yh))),
                             nzl = f2bf(-2.f * (z - bf2f(zh)));
        const unsigned short x2h = f2bf(x2), x2l = f2bf(x2 - bf2f(x2h));
        short8 a;
        if (kh == 0) {                   // k0-7
            a[0] = (short)nxh; a[1] = (short)nyh; a[2] = (short)nzh;
            a[3] = (short)nxh; a[4] = (short)nyh; a[5] = (short)nzh;
            a[6] = (short)nxl; a[7] = (short)nyl;
        } else {                         // k8-15
            a[0] = (short)nzl; a[1] = (short)nxl; a[2] = (short)nyl;
            a[3] = (short)nzl; a[4] = (short)x2h; a[5] = (short)x2l;
            a[6] = (short)ONEB; a[7] = (short)ONEB;
        }
        afr[g] = a;
        f32x16 v;
        #pragma unroll
        for (int i = 0; i < 16; ++i) v[i] = 1e30f;
        best[g] = v;
    }

    __shared__ uint4 sbuf[2048];         // 32 col-groups (1024 cols), 32 KB
    f32x16 zero;
    #pragma unroll
    for (int i = 0; i < 16; ++i) zero[i] = 0.f;

    int vfrags = 64;                     // 32-col groups in this segment
    if (dir == 0) { int rem = (L - c0 + 31) >> 5; vfrags = rem < 64 ? rem : 64; }

    for (int t = 0; t < 2; ++t) {
        const int fn0 = vfrags - t * 32;
        const int fn = fn0 < 32 ? fn0 : 32;
        if (fn <= 0) break;
        const uint4* src = bslab + ((size_t)(c0 >> 5) + t * 32) * 64;
        __syncthreads();                 // previous tile's readers done
        #pragma unroll
        for (int i = 0; i < 8; ++i) sbuf[tid + 256 * i] = src[tid + 256 * i];
        __syncthreads();

        #pragma unroll 2
        for (int f = 0; f < fn; ++f) {
            const short8 bfr = ((const short8*)sbuf)[f * 64 + lane];
            #pragma unroll
            for (int g = 0; g < GA; ++g) {
                const f32x16 d = __builtin_amdgcn_mfma_f32_32x32x16_bf16(
                    afr[g], bfr, zero, 0, 0, 0);
                best[g] = __builtin_elementwise_min(best[g], d);
            }
        }
    }

    // min over 32 cols (lanes within each 32-half), then float4 stores
    #pragma unroll
    for (int g = 0; g < GA; ++g) {
        f32x16 v = best[g];
        #pragma unroll
        for (int st = 1; st < 32; st <<= 1)
            #pragma unroll
            for (int i = 0; i < 16; ++i)
                v[i] = fminf(v[i], __shfl_xor(v[i], st, 64));
        if (m == 0) {                    // lanes 0 and 32 hold their half's rows
            float* rbase = slot + (wv * GA + g) * 32 + 4 * kh;
            #pragma unroll
            for (int q = 0; q < 4; ++q)  // rows 8q+4*kh .. +3
                *(float4*)(rbase + 8 * q) =
                    make_float4(v[4*q], v[4*q+1], v[4*q+2], v[4*q+3]);
        }
    }
}

__global__ __launch_bounds__(256) void chamfer_reduce_kernel(
    const float* __restrict__ partial, const int* __restrict__ lens,
    float* __restrict__ out)
{
    const int item = blockIdx.x * 256 + threadIdx.x;  // 2*N*P
    const int dir = item >> 15;
    const int b   = (item >> 13) & (N - 1);
    const int p   = item & (P - 1);
    const int L   = lens[b];

    float c = 0.f;
    if (dir == 0 || p < L) {
        const float* base = partial + (((size_t)dir * N + b) * NSEG) * P + p;
        float v = base[0];
        #pragma unroll
        for (int s = 1; s < NSEG; ++s) v = fminf(v, base[(size_t)s * P]);
        v = fmaxf(v, 0.f);
        c = dir ? v / ((float)L * (float)N) : v * (1.0f / ((float)P * (float)N));
    }
    #pragma unroll
    for (int off = 32; off; off >>= 1) c += __shfl_down(c, off, 64);
    __shared__ float acc[4];
    if ((threadIdx.x & 63) == 0) acc[threadIdx.x >> 6] = c;
    __syncthreads();
    if (threadIdx.x == 0) atomicAdd(out, acc[0] + acc[1] + acc[2] + acc[3]);
}

extern "C" void kernel_launch(void* const* d_in, const int* in_sizes, int n_in,
                              void* d_out, int out_size, void* d_ws, size_t ws_size,
                              hipStream_t stream)
{
    const float* pred = (const float*)d_in[0];
    const float* targ = (const float*)d_in[1];
    const int*   lens = (const int*)d_in[2];
    float* out = (float*)d_out;

    uint4* bpack   = (uint4*)d_ws;                       // 2 MB
    float* partial = (float*)(bpack + (size_t)2 * N * RECS);  // 1 MB

    hipMemsetAsync(out, 0, out_size * sizeof(float), stream);
    chamfer_prep_kernel<<<(2 * N * P) / 256, 256, 0, stream>>>(pred, targ, lens, bpack);
    chamfer_min_kernel<<<2 * N * RB * NSEG, 256, 0, stream>>>(pred, targ, lens, bpack, partial);
    chamfer_reduce_kernel<<<(2 * N * P) / 256, 256, 0, stream>>>(partial, lens, out);
}